// Round 1
// baseline (300.667 us; speedup 1.0000x reference)
//
#include <hip/hip_runtime.h>

// Problem constants (from reference setup_inputs)
#define NN 15828      // nodes
#define NE 253248     // edges
#define BB 64         // batch == wavefront size
#define HID 100       // hidden
#define NC 10         // classes
#define NEG 0.01f     // leaky slope

__device__ __forceinline__ float leaky(float v) { return v > 0.f ? v : NEG * v; }

// ---------------------------------------------------------------- degree count
__global__ void k_count(const int* __restrict__ src, const int* __restrict__ dst,
                        int* __restrict__ cnt_out, int* __restrict__ cnt_in) {
    int e = blockIdx.x * blockDim.x + threadIdx.x;
    if (e < NE) {
        atomicAdd(&cnt_out[src[e]], 1);
        atomicAdd(&cnt_in[dst[e]], 1);
    }
}

// --------------------------------------------------- normalization coefficients
__global__ void k_coef(const int* __restrict__ cnt_out, const int* __restrict__ cnt_in,
                       float* __restrict__ co, float* __restrict__ ci) {
    int n = blockIdx.x * blockDim.x + threadIdx.x;
    if (n < NN) {
        co[n] = 1.0f / sqrtf((float)max(cnt_out[n], 1));
        ci[n] = 1.0f / sqrtf((float)max(cnt_in[n], 1));
    }
}

// ------------------------------------------- xf[n,b] = in_feat[n,b] * co[n]
__global__ void k_scalefeat(const float* __restrict__ feat, const float* __restrict__ co,
                            float* __restrict__ xf) {
    int i = blockIdx.x * blockDim.x + threadIdx.x;   // grid sized exactly NN*BB
    xf[i] = feat[i] * co[i >> 6];
}

// ------------------------- exclusive scan of cnt_in -> rowptr, cursor (1 block)
__global__ void k_scan(const int* __restrict__ cnt_in, int* __restrict__ rowptr,
                       int* __restrict__ cursor) {
    __shared__ int sdata[1024];
    __shared__ int s_base;
    int tid = threadIdx.x;
    if (tid == 0) s_base = 0;
    __syncthreads();
    for (int start = 0; start < NN; start += 1024) {
        int i = start + tid;
        int v = (i < NN) ? cnt_in[i] : 0;
        sdata[tid] = v;
        __syncthreads();
        // Hillis-Steele inclusive scan
        for (int offd = 1; offd < 1024; offd <<= 1) {
            int t = (tid >= offd) ? sdata[tid - offd] : 0;
            __syncthreads();
            sdata[tid] += t;
            __syncthreads();
        }
        int incl = sdata[tid] + s_base;
        if (i < NN) {
            rowptr[i + 1] = incl;
            cursor[i] = incl - v;          // exclusive prefix
        }
        if (start == 0 && tid == 0) rowptr[0] = 0;
        __syncthreads();
        if (tid == 1023) s_base = incl;
        __syncthreads();
    }
}

// ---------------------------------------------------------------- CSR fill
__global__ void k_fill(const int* __restrict__ src, const int* __restrict__ dst,
                       int* __restrict__ cursor, int* __restrict__ csr) {
    int e = blockIdx.x * blockDim.x + threadIdx.x;
    if (e < NE) {
        int p = atomicAdd(&cursor[dst[e]], 1);
        csr[p] = src[e];
    }
}

// --------------- conv0 aggregation: s0[n,b] = ci[n] * sum_{in-edges} xf[src,b]
// one wave per node, lane = batch index
__global__ void k_agg0(const int* __restrict__ rowptr, const int* __restrict__ csr,
                       const float* __restrict__ xf, const float* __restrict__ ci,
                       float* __restrict__ s0) {
    int wave = (blockIdx.x * blockDim.x + threadIdx.x) >> 6;
    int lane = threadIdx.x & 63;
    if (wave >= NN) return;
    int beg = rowptr[wave], end = rowptr[wave + 1];
    float acc = 0.f;
    for (int k = beg; k < end; ++k) {
        int s = csr[k];
        acc += xf[(s << 6) + lane];
    }
    s0[(wave << 6) + lane] = ci[wave] * acc;
}

// ------ fused (conv0 weight+bias+leaky) x (conv1 pre-scale + @W1):
//   y[n,b] = co[n] * sum_f leaky(s0[n,b]*W0[f] + b0[f]) * W1[f]
__global__ void k_pw(const float* __restrict__ s0, const float* __restrict__ co,
                     const float* __restrict__ W0, const float* __restrict__ b0,
                     const float* __restrict__ W1, float* __restrict__ y) {
    __shared__ float w0s[HID], b0s[HID], w1s[HID];
    int tid = threadIdx.x;
    if (tid < HID) { w0s[tid] = W0[tid]; b0s[tid] = b0[tid]; w1s[tid] = W1[tid]; }
    __syncthreads();
    int i = blockIdx.x * blockDim.x + tid;   // grid sized exactly NN*BB
    float t = s0[i];
    float acc = 0.f;
#pragma unroll 4
    for (int f = 0; f < HID; ++f) {
        float v = fmaf(t, w0s[f], b0s[f]);
        v = v > 0.f ? v : NEG * v;
        acc = fmaf(v, w1s[f], acc);
    }
    y[i] = acc * co[i >> 6];
}

// -------- conv1 aggregation + bias + leaky: h1[n,b] = leaky(ci[n]*sum y + b1)
__global__ void k_agg1(const int* __restrict__ rowptr, const int* __restrict__ csr,
                       const float* __restrict__ y, const float* __restrict__ ci,
                       const float* __restrict__ b1, float* __restrict__ h1) {
    int wave = (blockIdx.x * blockDim.x + threadIdx.x) >> 6;
    int lane = threadIdx.x & 63;
    if (wave >= NN) return;
    int beg = rowptr[wave], end = rowptr[wave + 1];
    float acc = 0.f;
    for (int k = beg; k < end; ++k) {
        int s = csr[k];
        acc += y[(s << 6) + lane];
    }
    float v = fmaf(ci[wave], acc, b1[0]);
    h1[(wave << 6) + lane] = leaky(v);
}

// ------- split-K GEMM: part[s][f][b] = sum_{n in chunk s} h1[n,b]*lw0[f,n]
// block = 4 waves (4 f's), lane = b. h1 reads coalesced, lw0 broadcast.
#define NSPLIT 16
#define NCHUNK 990   // ceil(15828/16)
__global__ void k_gemm(const float* __restrict__ h1, const float* __restrict__ lw0,
                       float* __restrict__ part) {
    int lane = threadIdx.x & 63;
    int w = threadIdx.x >> 6;
    int f = blockIdx.x * 4 + w;       // 0..99
    int s = blockIdx.y;               // 0..15
    int n0 = s * NCHUNK;
    int n1 = min(NN, n0 + NCHUNK);
    const float* hp = h1 + (size_t)n0 * BB + lane;
    const float* wp = lw0 + (size_t)f * NN;
    float acc = 0.f;
#pragma unroll 4
    for (int n = n0; n < n1; ++n) {
        acc = fmaf(*hp, wp[n], acc);
        hp += BB;
    }
    part[(size_t)s * (HID * BB) + f * BB + lane] = acc;
}

// ---------------- reduce splits + bias + leaky -> out1[b][f]
__global__ void k_red(const float* __restrict__ part, const float* __restrict__ lb0,
                      float* __restrict__ out1) {
    int i = blockIdx.x * blockDim.x + threadIdx.x;   // over HID*BB = 6400
    if (i >= HID * BB) return;
    float a = 0.f;
#pragma unroll
    for (int s = 0; s < NSPLIT; ++s) a += part[(size_t)s * (HID * BB) + i];
    int f = i >> 6, b = i & 63;
    float v = a + lb0[f];
    out1[b * HID + f] = leaky(v);
}

// ---------------- tiny MLP tail: layer2 (100x100) + layer3 (10x100)
__global__ void k_mlp23(const float* __restrict__ out1, const float* __restrict__ lw2,
                        const float* __restrict__ lb2, const float* __restrict__ lw3,
                        const float* __restrict__ lb3, float* __restrict__ out) {
    __shared__ float hin[HID], h3[HID];
    int b = blockIdx.x, tid = threadIdx.x;
    if (tid < HID) hin[tid] = out1[b * HID + tid];
    __syncthreads();
    if (tid < HID) {
        float acc = lb2[tid];
#pragma unroll 4
        for (int k = 0; k < HID; ++k) acc = fmaf(hin[k], lw2[tid * HID + k], acc);
        h3[tid] = leaky(acc);
    }
    __syncthreads();
    if (tid < NC) {
        float acc = lb3[tid];
#pragma unroll 4
        for (int j = 0; j < HID; ++j) acc = fmaf(h3[j], lw3[tid * HID + j], acc);
        out[b * NC + tid] = leaky(acc);
    }
}

extern "C" void kernel_launch(void* const* d_in, const int* in_sizes, int n_in,
                              void* d_out, int out_size, void* d_ws, size_t ws_size,
                              hipStream_t stream) {
    const float* in_feat = (const float*)d_in[0];
    const int*   eidx    = (const int*)d_in[1];
    const int*   src     = eidx;
    const int*   dst     = eidx + NE;
    const float* W0  = (const float*)d_in[2];
    const float* b0  = (const float*)d_in[3];
    const float* W1  = (const float*)d_in[4];
    const float* b1  = (const float*)d_in[5];
    const float* lw0 = (const float*)d_in[6];
    const float* lb0 = (const float*)d_in[7];
    const float* lw2 = (const float*)d_in[8];
    const float* lb2 = (const float*)d_in[9];
    const float* lw3 = (const float*)d_in[10];
    const float* lb3 = (const float*)d_in[11];
    float* out = (float*)d_out;

    // workspace carve-up (aligned to 512B)
    char* ws = (char*)d_ws;
    size_t off = 0;
    auto alloc = [&](size_t bytes) -> char* {
        char* p = ws + off;
        off += (bytes + 511) & ~(size_t)511;
        return p;
    };
    int* cnt_out = (int*)alloc((size_t)NN * 4);
    int* cnt_in  = (int*)alloc((size_t)NN * 4);
    int* rowptr  = (int*)alloc((size_t)(NN + 1) * 4);
    int* cursor  = (int*)alloc((size_t)NN * 4);
    int* csr     = (int*)alloc((size_t)NE * 4);
    float* co    = (float*)alloc((size_t)NN * 4);
    float* ci    = (float*)alloc((size_t)NN * 4);
    float* bufA  = (float*)alloc((size_t)NN * BB * 4);  // xf, later h1
    float* bufB  = (float*)alloc((size_t)NN * BB * 4);  // s0, later part+out1
    float* bufC  = (float*)alloc((size_t)NN * BB * 4);  // y
    float* part  = bufB;                                 // s0 is dead by then
    float* out1  = bufB + (size_t)NSPLIT * HID * BB;

    hipMemsetAsync(cnt_out, 0, (size_t)NN * 4, stream);
    hipMemsetAsync(cnt_in, 0, (size_t)NN * 4, stream);

    k_count<<<(NE + 255) / 256, 256, 0, stream>>>(src, dst, cnt_out, cnt_in);
    k_coef<<<(NN + 255) / 256, 256, 0, stream>>>(cnt_out, cnt_in, co, ci);
    k_scalefeat<<<(NN * BB) / 256, 256, 0, stream>>>(in_feat, co, bufA);
    k_scan<<<1, 1024, 0, stream>>>(cnt_in, rowptr, cursor);
    k_fill<<<(NE + 255) / 256, 256, 0, stream>>>(src, dst, cursor, csr);
    k_agg0<<<NN / 4, 256, 0, stream>>>(rowptr, csr, bufA, ci, bufB);
    k_pw<<<(NN * BB) / 256, 256, 0, stream>>>(bufB, co, W0, b0, W1, bufC);
    k_agg1<<<NN / 4, 256, 0, stream>>>(rowptr, csr, bufC, ci, b1, bufA);
    k_gemm<<<dim3(HID / 4, NSPLIT), 256, 0, stream>>>(bufA, lw0, part);
    k_red<<<(HID * BB + 255) / 256, 256, 0, stream>>>(part, lb0, out1);
    k_mlp23<<<BB, 128, 0, stream>>>(out1, lw2, lb2, lw3, lb3, out);
}

// Round 2
// 230.711 us; speedup vs baseline: 1.3032x; 1.3032x over previous
//
#include <hip/hip_runtime.h>

// Problem constants (from reference setup_inputs)
#define NN 15828      // nodes
#define NE 253248     // edges
#define BB 64         // batch == wavefront size
#define HID 100       // hidden
#define NC 10         // classes
#define NEG 0.01f     // leaky slope

__device__ __forceinline__ float leaky(float v) { return v > 0.f ? v : NEG * v; }

// ---------------------------------------------------------------- degree count
__global__ void k_count(const int* __restrict__ src, const int* __restrict__ dst,
                        int* __restrict__ cnt_out, int* __restrict__ cnt_in) {
    int e = blockIdx.x * blockDim.x + threadIdx.x;
    if (e < NE) {
        atomicAdd(&cnt_out[src[e]], 1);
        atomicAdd(&cnt_in[dst[e]], 1);
    }
}

// --------------------------------------------------- normalization coefficients
__global__ void k_coef(const int* __restrict__ cnt_out, const int* __restrict__ cnt_in,
                       float* __restrict__ co, float* __restrict__ ci) {
    int n = blockIdx.x * blockDim.x + threadIdx.x;
    if (n < NN) {
        co[n] = 1.0f / sqrtf((float)max(cnt_out[n], 1));
        ci[n] = 1.0f / sqrtf((float)max(cnt_in[n], 1));
    }
}

// ------------------------------------------- xf[n,b] = in_feat[n,b] * co[n]
__global__ void k_scalefeat(const float* __restrict__ feat, const float* __restrict__ co,
                            float* __restrict__ xf) {
    int i = blockIdx.x * blockDim.x + threadIdx.x;   // grid sized exactly NN*BB
    xf[i] = feat[i] * co[i >> 6];
}

// ---- exclusive scan of cnt_in -> rowptr[0..NN], cursor (1 block, 1 barrier)
__global__ void k_scan(const int* __restrict__ cnt, int* __restrict__ rowptr,
                       int* __restrict__ cursor) {
    __shared__ int wsum[4];
    int tid = threadIdx.x;            // 256 threads
    int lane = tid & 63, w = tid >> 6;
    const int PER = (NN + 255) / 256; // 62
    int s = tid * PER, e = min(NN, s + PER);
    int sum = 0;
    for (int i = s; i < e; ++i) sum += cnt[i];
    // inclusive wave scan of per-thread sums
    int v = sum;
    for (int off = 1; off < 64; off <<= 1) {
        int t = __shfl_up(v, off, 64);
        if (lane >= off) v += t;
    }
    if (lane == 63) wsum[w] = v;
    __syncthreads();
    int base = 0;
    for (int i = 0; i < w; ++i) base += wsum[i];
    int run = base + v - sum;         // exclusive prefix for this thread's range
    for (int i = s; i < e; ++i) {
        int c = cnt[i];
        rowptr[i] = run;
        cursor[i] = run;
        run += c;
    }
    if (tid == 255) rowptr[NN] = NE;
}

// ---------------------------------------------------------------- CSR fill
__global__ void k_fill(const int* __restrict__ src, const int* __restrict__ dst,
                       int* __restrict__ cursor, int* __restrict__ csr) {
    int e = blockIdx.x * blockDim.x + threadIdx.x;
    if (e < NE) {
        int p = atomicAdd(&cursor[dst[e]], 1);
        csr[p] = src[e];
    }
}

// --- fused conv0-aggregate + conv0 weight/bias/leaky + conv1 weight + src-scale:
//   s0 = ci[n] * sum_{in-edges} xf[src,b]
//   y[n,b] = co[n] * sum_f leaky(s0*W0[f] + b0[f]) * W1[f]
// one wave per node, lane = batch index
__global__ void k_agg0pw(const int* __restrict__ rowptr, const int* __restrict__ csr,
                         const float* __restrict__ xf, const float* __restrict__ ci,
                         const float* __restrict__ co,
                         const float* __restrict__ W0, const float* __restrict__ b0,
                         const float* __restrict__ W1, float* __restrict__ y) {
    __shared__ __align__(16) float w0s[HID], b0s[HID], w1s[HID];
    int tid = threadIdx.x;
    if (tid < HID) { w0s[tid] = W0[tid]; b0s[tid] = b0[tid]; w1s[tid] = W1[tid]; }
    __syncthreads();
    int node = (blockIdx.x * blockDim.x + tid) >> 6;   // grid exactly NN/4 blocks
    int lane = tid & 63;
    int k = rowptr[node], kend = rowptr[node + 1];
    float a0 = 0.f, a1 = 0.f, a2 = 0.f, a3 = 0.f;
    for (; k + 3 < kend; k += 4) {
        int i0 = csr[k], i1 = csr[k + 1], i2 = csr[k + 2], i3 = csr[k + 3];
        a0 += xf[(i0 << 6) + lane];
        a1 += xf[(i1 << 6) + lane];
        a2 += xf[(i2 << 6) + lane];
        a3 += xf[(i3 << 6) + lane];
    }
    for (; k < kend; ++k) a0 += xf[(csr[k] << 6) + lane];
    float t = ci[node] * ((a0 + a1) + (a2 + a3));
    float acc = 0.f;
#pragma unroll
    for (int f = 0; f < HID; f += 4) {
        float4 w0v = *(const float4*)&w0s[f];
        float4 b0v = *(const float4*)&b0s[f];
        float4 w1v = *(const float4*)&w1s[f];
        float v0 = fmaf(t, w0v.x, b0v.x); v0 = v0 > 0.f ? v0 : NEG * v0; acc = fmaf(v0, w1v.x, acc);
        float v1 = fmaf(t, w0v.y, b0v.y); v1 = v1 > 0.f ? v1 : NEG * v1; acc = fmaf(v1, w1v.y, acc);
        float v2 = fmaf(t, w0v.z, b0v.z); v2 = v2 > 0.f ? v2 : NEG * v2; acc = fmaf(v2, w1v.z, acc);
        float v3 = fmaf(t, w0v.w, b0v.w); v3 = v3 > 0.f ? v3 : NEG * v3; acc = fmaf(v3, w1v.w, acc);
    }
    y[(node << 6) + lane] = acc * co[node];
}

// -------- conv1 aggregation + bias + leaky: h1[n,b] = leaky(ci[n]*sum y + b1)
__global__ void k_agg1(const int* __restrict__ rowptr, const int* __restrict__ csr,
                       const float* __restrict__ y, const float* __restrict__ ci,
                       const float* __restrict__ b1, float* __restrict__ h1) {
    int node = (blockIdx.x * blockDim.x + threadIdx.x) >> 6;
    int lane = threadIdx.x & 63;
    int k = rowptr[node], kend = rowptr[node + 1];
    float a0 = 0.f, a1 = 0.f, a2 = 0.f, a3 = 0.f;
    for (; k + 3 < kend; k += 4) {
        int i0 = csr[k], i1 = csr[k + 1], i2 = csr[k + 2], i3 = csr[k + 3];
        a0 += y[(i0 << 6) + lane];
        a1 += y[(i1 << 6) + lane];
        a2 += y[(i2 << 6) + lane];
        a3 += y[(i3 << 6) + lane];
    }
    for (; k < kend; ++k) a0 += y[(csr[k] << 6) + lane];
    float v = fmaf(ci[node], (a0 + a1) + (a2 + a3), b1[0]);
    h1[(node << 6) + lane] = leaky(v);
}

// ------- split-K GEMM: part[s][f][b] = sum_{n in chunk s} h1[n,b]*lw0[f,n]
// block = 4 waves; each wave computes 4 consecutive f rows (4x h1 reuse in-reg).
// lane = b -> h1 reads coalesced 256B; lw0 read as uniform float4 broadcast.
#define NSPLIT 64
#define NCHUNK 248   // 64*248 = 15872 >= 15828; all chunk lengths divisible by 4
__global__ void k_gemm(const float* __restrict__ h1, const float* __restrict__ lw0,
                       float* __restrict__ part) {
    int lane = threadIdx.x & 63;
    int w = threadIdx.x >> 6;
    int f0 = blockIdx.x * 16 + w * 4;     // 0,4,...,108
    int s = blockIdx.y;                   // 0..63
    if (f0 >= HID) return;
    int n0 = s * NCHUNK;
    int n1 = min(NN, n0 + NCHUNK);
    const float* hp  = h1 + (size_t)n0 * BB + lane;
    const float* w0p = lw0 + (size_t)(f0 + 0) * NN;
    const float* w1p = lw0 + (size_t)(f0 + 1) * NN;
    const float* w2p = lw0 + (size_t)(f0 + 2) * NN;
    const float* w3p = lw0 + (size_t)(f0 + 3) * NN;
    float a0 = 0.f, a1 = 0.f, a2 = 0.f, a3 = 0.f;
    for (int n = n0; n < n1; n += 4) {
        float4 wa = *(const float4*)(w0p + n);
        float4 wb = *(const float4*)(w1p + n);
        float4 wc = *(const float4*)(w2p + n);
        float4 wd = *(const float4*)(w3p + n);
        float h0 = hp[0], h1v = hp[64], h2 = hp[128], h3 = hp[192];
        a0 = fmaf(h0, wa.x, a0); a1 = fmaf(h0, wb.x, a1); a2 = fmaf(h0, wc.x, a2); a3 = fmaf(h0, wd.x, a3);
        a0 = fmaf(h1v, wa.y, a0); a1 = fmaf(h1v, wb.y, a1); a2 = fmaf(h1v, wc.y, a2); a3 = fmaf(h1v, wd.y, a3);
        a0 = fmaf(h2, wa.z, a0); a1 = fmaf(h2, wb.z, a1); a2 = fmaf(h2, wc.z, a2); a3 = fmaf(h2, wd.z, a3);
        a0 = fmaf(h3, wa.w, a0); a1 = fmaf(h3, wb.w, a1); a2 = fmaf(h3, wc.w, a2); a3 = fmaf(h3, wd.w, a3);
        hp += 256;
    }
    size_t base = (size_t)s * (HID * BB);
    part[base + (f0 + 0) * BB + lane] = a0;
    part[base + (f0 + 1) * BB + lane] = a1;
    part[base + (f0 + 2) * BB + lane] = a2;
    part[base + (f0 + 3) * BB + lane] = a3;
}

// ---------------- reduce splits + bias + leaky -> out1[b][f]
__global__ void k_red(const float* __restrict__ part, const float* __restrict__ lb0,
                      float* __restrict__ out1) {
    int i = blockIdx.x * blockDim.x + threadIdx.x;   // over HID*BB = 6400
    if (i >= HID * BB) return;
    float a = 0.f;
#pragma unroll 8
    for (int s = 0; s < NSPLIT; ++s) a += part[(size_t)s * (HID * BB) + i];
    int f = i >> 6, b = i & 63;
    float v = a + lb0[f];
    out1[b * HID + f] = leaky(v);
}

// ---------------- tiny MLP tail: layer2 (100x100) + layer3 (10x100)
__global__ void k_mlp23(const float* __restrict__ out1, const float* __restrict__ lw2,
                        const float* __restrict__ lb2, const float* __restrict__ lw3,
                        const float* __restrict__ lb3, float* __restrict__ out) {
    __shared__ __align__(16) float hin[HID], h3[HID];
    int b = blockIdx.x, tid = threadIdx.x;
    if (tid < HID) hin[tid] = out1[b * HID + tid];
    __syncthreads();
    if (tid < HID) {
        float acc = lb2[tid];
        const float* r = lw2 + tid * HID;
#pragma unroll 4
        for (int k = 0; k < HID; ++k) acc = fmaf(hin[k], r[k], acc);
        h3[tid] = leaky(acc);
    }
    __syncthreads();
    if (tid < NC) {
        float acc = lb3[tid];
        const float* r = lw3 + tid * HID;
#pragma unroll 4
        for (int j = 0; j < HID; ++j) acc = fmaf(h3[j], r[j], acc);
        out[b * NC + tid] = leaky(acc);
    }
}

extern "C" void kernel_launch(void* const* d_in, const int* in_sizes, int n_in,
                              void* d_out, int out_size, void* d_ws, size_t ws_size,
                              hipStream_t stream) {
    const float* in_feat = (const float*)d_in[0];
    const int*   eidx    = (const int*)d_in[1];
    const int*   src     = eidx;
    const int*   dst     = eidx + NE;
    const float* W0  = (const float*)d_in[2];
    const float* b0  = (const float*)d_in[3];
    const float* W1  = (const float*)d_in[4];
    const float* b1  = (const float*)d_in[5];
    const float* lw0 = (const float*)d_in[6];
    const float* lb0 = (const float*)d_in[7];
    const float* lw2 = (const float*)d_in[8];
    const float* lb2 = (const float*)d_in[9];
    const float* lw3 = (const float*)d_in[10];
    const float* lb3 = (const float*)d_in[11];
    float* out = (float*)d_out;

    // workspace carve-up (aligned to 512B)
    char* ws = (char*)d_ws;
    size_t off = 0;
    auto alloc = [&](size_t bytes) -> char* {
        char* p = ws + off;
        off += (bytes + 511) & ~(size_t)511;
        return p;
    };
    int* cnt_out = (int*)alloc((size_t)NN * 4);
    int* cnt_in  = (int*)alloc((size_t)NN * 4);
    int* rowptr  = (int*)alloc((size_t)(NN + 1) * 4);
    int* cursor  = (int*)alloc((size_t)NN * 4);
    int* csr     = (int*)alloc((size_t)NE * 4);
    float* co    = (float*)alloc((size_t)NN * 4);
    float* ci    = (float*)alloc((size_t)NN * 4);
    float* bufA  = (float*)alloc((size_t)NN * BB * 4);  // xf -> (dead) -> part+out1
    float* bufB  = (float*)alloc((size_t)NN * BB * 4);  // h1
    float* bufC  = (float*)alloc((size_t)NN * BB * 4);  // y
    float* part  = bufA;                                 // xf dead after agg0pw
    float* out1  = bufA + (size_t)NSPLIT * HID * BB;

    hipMemsetAsync(cnt_out, 0, (size_t)NN * 4, stream);
    hipMemsetAsync(cnt_in, 0, (size_t)NN * 4, stream);

    k_count<<<(NE + 255) / 256, 256, 0, stream>>>(src, dst, cnt_out, cnt_in);
    k_coef<<<(NN + 255) / 256, 256, 0, stream>>>(cnt_out, cnt_in, co, ci);
    k_scalefeat<<<(NN * BB) / 256, 256, 0, stream>>>(in_feat, co, bufA);
    k_scan<<<1, 256, 0, stream>>>(cnt_in, rowptr, cursor);
    k_fill<<<(NE + 255) / 256, 256, 0, stream>>>(src, dst, cursor, csr);
    k_agg0pw<<<NN / 4, 256, 0, stream>>>(rowptr, csr, bufA, ci, co, W0, b0, W1, bufC);
    k_agg1<<<NN / 4, 256, 0, stream>>>(rowptr, csr, bufC, ci, b1, bufB);
    k_gemm<<<dim3(7, NSPLIT), 256, 0, stream>>>(bufB, lw0, part);
    k_red<<<(HID * BB + 255) / 256, 256, 0, stream>>>(part, lb0, out1);
    k_mlp23<<<BB, 128, 0, stream>>>(out1, lw2, lb2, lw3, lb3, out);
}

// Round 3
// 225.169 us; speedup vs baseline: 1.3353x; 1.0246x over previous
//
#include <hip/hip_runtime.h>

// Problem constants (from reference setup_inputs)
#define NN 15828      // nodes
#define NE 253248     // edges (divisible by 4)
#define BB 64         // batch == wavefront size
#define HID 100       // hidden
#define NC 10         // classes
#define NEG 0.01f     // leaky slope

__device__ __forceinline__ float leaky(float v) { return v > 0.f ? v : NEG * v; }

// -------------------------- degree count: 4 edges per thread via int4 loads
__global__ void k_count(const int* __restrict__ src, const int* __restrict__ dst,
                        int* __restrict__ cnt_out, int* __restrict__ cnt_in) {
    int t = blockIdx.x * blockDim.x + threadIdx.x;
    int e = t * 4;
    if (e + 3 < NE) {
        int4 s = *(const int4*)(src + e);
        int4 d = *(const int4*)(dst + e);
        atomicAdd(&cnt_out[s.x], 1); atomicAdd(&cnt_out[s.y], 1);
        atomicAdd(&cnt_out[s.z], 1); atomicAdd(&cnt_out[s.w], 1);
        atomicAdd(&cnt_in[d.x], 1);  atomicAdd(&cnt_in[d.y], 1);
        atomicAdd(&cnt_in[d.z], 1);  atomicAdd(&cnt_in[d.w], 1);
    } else {
        for (; e < NE; ++e) { atomicAdd(&cnt_out[src[e]], 1); atomicAdd(&cnt_in[dst[e]], 1); }
    }
}

// ---- coef + scale fused: xf[n,b] = feat[n,b]/sqrt(deg_out); also emit co, ci
__global__ void k_coefscale(const float* __restrict__ feat,
                            const int* __restrict__ cnt_out, const int* __restrict__ cnt_in,
                            float* __restrict__ co, float* __restrict__ ci,
                            float* __restrict__ xf) {
    int i = blockIdx.x * blockDim.x + threadIdx.x;   // grid sized exactly NN*BB
    int n = i >> 6, lane = i & 63;
    float c = 1.0f / sqrtf((float)max(cnt_out[n], 1));
    xf[i] = feat[i] * c;
    if (lane == 0) co[n] = c;
    if (lane == 1) ci[n] = 1.0f / sqrtf((float)max(cnt_in[n], 1));
}

// ---- exclusive scan of cnt_in -> rowptr[0..NN], cursor (1 block, 1 barrier)
__global__ void k_scan(const int* __restrict__ cnt, int* __restrict__ rowptr,
                       int* __restrict__ cursor) {
    __shared__ int wsum[4];
    int tid = threadIdx.x;            // 256 threads
    int lane = tid & 63, w = tid >> 6;
    const int PER = (NN + 255) / 256; // 62
    int s = tid * PER, e = min(NN, s + PER);
    int sum = 0;
    for (int i = s; i < e; ++i) sum += cnt[i];
    int v = sum;
    for (int off = 1; off < 64; off <<= 1) {
        int t = __shfl_up(v, off, 64);
        if (lane >= off) v += t;
    }
    if (lane == 63) wsum[w] = v;
    __syncthreads();
    int base = 0;
    for (int i = 0; i < w; ++i) base += wsum[i];
    int run = base + v - sum;         // exclusive prefix for this thread's range
    for (int i = s; i < e; ++i) {
        int c = cnt[i];
        rowptr[i] = run;
        cursor[i] = run;
        run += c;
    }
    if (tid == 255) rowptr[NN] = NE;
}

// -------------------------- CSR fill: 4 edges per thread via int4 loads
__global__ void k_fill(const int* __restrict__ src, const int* __restrict__ dst,
                       int* __restrict__ cursor, int* __restrict__ csr) {
    int t = blockIdx.x * blockDim.x + threadIdx.x;
    int e = t * 4;
    if (e + 3 < NE) {
        int4 s = *(const int4*)(src + e);
        int4 d = *(const int4*)(dst + e);
        csr[atomicAdd(&cursor[d.x], 1)] = s.x;
        csr[atomicAdd(&cursor[d.y], 1)] = s.y;
        csr[atomicAdd(&cursor[d.z], 1)] = s.z;
        csr[atomicAdd(&cursor[d.w], 1)] = s.w;
    } else {
        for (; e < NE; ++e) csr[atomicAdd(&cursor[dst[e]], 1)] = src[e];
    }
}

// --- fused conv0-aggregate + conv0 weight/bias/leaky + conv1 weight + src-scale:
//   s0 = ci[n] * sum_{in-edges} xf[src,b]
//   y[n,b] = co[n] * sum_f leaky(s0*W0[f] + b0[f]) * W1[f]
// one wave per node, lane = batch index
__global__ void k_agg0pw(const int* __restrict__ rowptr, const int* __restrict__ csr,
                         const float* __restrict__ xf, const float* __restrict__ ci,
                         const float* __restrict__ co,
                         const float* __restrict__ W0, const float* __restrict__ b0,
                         const float* __restrict__ W1, float* __restrict__ y) {
    __shared__ __align__(16) float w0s[HID], b0s[HID], w1s[HID];
    int tid = threadIdx.x;
    if (tid < HID) { w0s[tid] = W0[tid]; b0s[tid] = b0[tid]; w1s[tid] = W1[tid]; }
    __syncthreads();
    int node = (blockIdx.x * blockDim.x + tid) >> 6;   // grid exactly NN/4 blocks
    int lane = tid & 63;
    int k = rowptr[node], kend = rowptr[node + 1];
    float a0 = 0.f, a1 = 0.f, a2 = 0.f, a3 = 0.f;
    for (; k + 3 < kend; k += 4) {
        int i0 = csr[k], i1 = csr[k + 1], i2 = csr[k + 2], i3 = csr[k + 3];
        a0 += xf[(i0 << 6) + lane];
        a1 += xf[(i1 << 6) + lane];
        a2 += xf[(i2 << 6) + lane];
        a3 += xf[(i3 << 6) + lane];
    }
    for (; k < kend; ++k) a0 += xf[(csr[k] << 6) + lane];
    float t = ci[node] * ((a0 + a1) + (a2 + a3));
    float acc = 0.f;
#pragma unroll
    for (int f = 0; f < HID; f += 4) {
        float4 w0v = *(const float4*)&w0s[f];
        float4 b0v = *(const float4*)&b0s[f];
        float4 w1v = *(const float4*)&w1s[f];
        float v0 = fmaf(t, w0v.x, b0v.x); v0 = v0 > 0.f ? v0 : NEG * v0; acc = fmaf(v0, w1v.x, acc);
        float v1 = fmaf(t, w0v.y, b0v.y); v1 = v1 > 0.f ? v1 : NEG * v1; acc = fmaf(v1, w1v.y, acc);
        float v2 = fmaf(t, w0v.z, b0v.z); v2 = v2 > 0.f ? v2 : NEG * v2; acc = fmaf(v2, w1v.z, acc);
        float v3 = fmaf(t, w0v.w, b0v.w); v3 = v3 > 0.f ? v3 : NEG * v3; acc = fmaf(v3, w1v.w, acc);
    }
    y[(node << 6) + lane] = acc * co[node];
}

// -------- conv1 aggregation + bias + leaky: h1[n,b] = leaky(ci[n]*sum y + b1)
__global__ void k_agg1(const int* __restrict__ rowptr, const int* __restrict__ csr,
                       const float* __restrict__ y, const float* __restrict__ ci,
                       const float* __restrict__ b1, float* __restrict__ h1) {
    int node = (blockIdx.x * blockDim.x + threadIdx.x) >> 6;
    int lane = threadIdx.x & 63;
    int k = rowptr[node], kend = rowptr[node + 1];
    float a0 = 0.f, a1 = 0.f, a2 = 0.f, a3 = 0.f;
    for (; k + 3 < kend; k += 4) {
        int i0 = csr[k], i1 = csr[k + 1], i2 = csr[k + 2], i3 = csr[k + 3];
        a0 += y[(i0 << 6) + lane];
        a1 += y[(i1 << 6) + lane];
        a2 += y[(i2 << 6) + lane];
        a3 += y[(i3 << 6) + lane];
    }
    for (; k < kend; ++k) a0 += y[(csr[k] << 6) + lane];
    float v = fmaf(ci[node], (a0 + a1) + (a2 + a3), b1[0]);
    h1[(node << 6) + lane] = leaky(v);
}

// ------- split-K GEMM with atomic epilogue:
//   out1acc[f*64+b] += sum_{n in chunk s} h1[n,b]*lw0[f,n]
// block = 4 waves; each wave computes 4 consecutive f rows (4x h1 reuse in-reg).
// lane = b -> h1 reads coalesced 256B; lw0 read as uniform float4 broadcast.
#define NSPLIT 64
#define NCHUNK 248   // 64*248 = 15872 >= 15828; all chunk lengths divisible by 4
__global__ void k_gemm(const float* __restrict__ h1, const float* __restrict__ lw0,
                       float* __restrict__ out1acc) {
    int lane = threadIdx.x & 63;
    int w = threadIdx.x >> 6;
    int f0 = blockIdx.x * 16 + w * 4;     // 0,4,...,108
    int s = blockIdx.y;                   // 0..63
    if (f0 >= HID) return;
    int n0 = s * NCHUNK;
    int n1 = min(NN, n0 + NCHUNK);
    const float* hp  = h1 + (size_t)n0 * BB + lane;
    const float* w0p = lw0 + (size_t)(f0 + 0) * NN;
    const float* w1p = lw0 + (size_t)(f0 + 1) * NN;
    const float* w2p = lw0 + (size_t)(f0 + 2) * NN;
    const float* w3p = lw0 + (size_t)(f0 + 3) * NN;
    float a0 = 0.f, a1 = 0.f, a2 = 0.f, a3 = 0.f;
    for (int n = n0; n < n1; n += 4) {
        float4 wa = *(const float4*)(w0p + n);
        float4 wb = *(const float4*)(w1p + n);
        float4 wc = *(const float4*)(w2p + n);
        float4 wd = *(const float4*)(w3p + n);
        float h0 = hp[0], h1v = hp[64], h2 = hp[128], h3 = hp[192];
        a0 = fmaf(h0, wa.x, a0); a1 = fmaf(h0, wb.x, a1); a2 = fmaf(h0, wc.x, a2); a3 = fmaf(h0, wd.x, a3);
        a0 = fmaf(h1v, wa.y, a0); a1 = fmaf(h1v, wb.y, a1); a2 = fmaf(h1v, wc.y, a2); a3 = fmaf(h1v, wd.y, a3);
        a0 = fmaf(h2, wa.z, a0); a1 = fmaf(h2, wb.z, a1); a2 = fmaf(h2, wc.z, a2); a3 = fmaf(h2, wd.z, a3);
        a0 = fmaf(h3, wa.w, a0); a1 = fmaf(h3, wb.w, a1); a2 = fmaf(h3, wc.w, a2); a3 = fmaf(h3, wd.w, a3);
        hp += 256;
    }
    atomicAdd(&out1acc[(f0 + 0) * BB + lane], a0);
    atomicAdd(&out1acc[(f0 + 1) * BB + lane], a1);
    atomicAdd(&out1acc[(f0 + 2) * BB + lane], a2);
    atomicAdd(&out1acc[(f0 + 3) * BB + lane], a3);
}

// ---------------- tail: bias+leaky on out1acc, then layer2 (100x100) + layer3 (10x100)
// one block per batch element b
__global__ void k_mlp23(const float* __restrict__ out1acc, const float* __restrict__ lb0,
                        const float* __restrict__ lw2, const float* __restrict__ lb2,
                        const float* __restrict__ lw3, const float* __restrict__ lb3,
                        float* __restrict__ out) {
    __shared__ __align__(16) float hin[HID], h3[HID];
    int b = blockIdx.x, tid = threadIdx.x;
    if (tid < HID) hin[tid] = leaky(out1acc[tid * BB + b] + lb0[tid]);
    __syncthreads();
    if (tid < HID) {
        float acc = lb2[tid];
        const float* r = lw2 + tid * HID;
#pragma unroll 4
        for (int k = 0; k < HID; ++k) acc = fmaf(hin[k], r[k], acc);
        h3[tid] = leaky(acc);
    }
    __syncthreads();
    if (tid < NC) {
        float acc = lb3[tid];
        const float* r = lw3 + tid * HID;
#pragma unroll 4
        for (int j = 0; j < HID; ++j) acc = fmaf(h3[j], r[j], acc);
        out[b * NC + tid] = leaky(acc);
    }
}

extern "C" void kernel_launch(void* const* d_in, const int* in_sizes, int n_in,
                              void* d_out, int out_size, void* d_ws, size_t ws_size,
                              hipStream_t stream) {
    const float* in_feat = (const float*)d_in[0];
    const int*   eidx    = (const int*)d_in[1];
    const int*   src     = eidx;
    const int*   dst     = eidx + NE;
    const float* W0  = (const float*)d_in[2];
    const float* b0  = (const float*)d_in[3];
    const float* W1  = (const float*)d_in[4];
    const float* b1  = (const float*)d_in[5];
    const float* lw0 = (const float*)d_in[6];
    const float* lb0 = (const float*)d_in[7];
    const float* lw2 = (const float*)d_in[8];
    const float* lb2 = (const float*)d_in[9];
    const float* lw3 = (const float*)d_in[10];
    const float* lb3 = (const float*)d_in[11];
    float* out = (float*)d_out;

    // workspace carve-up (aligned to 512B)
    char* ws = (char*)d_ws;
    size_t off = 0;
    auto alloc = [&](size_t bytes) -> char* {
        char* p = ws + off;
        off += (bytes + 511) & ~(size_t)511;
        return p;
    };
    // zero-region: cnt_out | cnt_in | out1acc — one memset covers all three
    char* zbase = ws;
    int*   cnt_out = (int*)alloc((size_t)NN * 4);
    int*   cnt_in  = (int*)alloc((size_t)NN * 4);
    float* out1acc = (float*)alloc((size_t)HID * BB * 4);
    size_t zbytes  = off;
    int* rowptr  = (int*)alloc((size_t)(NN + 1) * 4);
    int* cursor  = (int*)alloc((size_t)NN * 4);
    int* csr     = (int*)alloc((size_t)NE * 4);
    float* co    = (float*)alloc((size_t)NN * 4);
    float* ci    = (float*)alloc((size_t)NN * 4);
    float* xf    = (float*)alloc((size_t)NN * BB * 4);
    float* y     = (float*)alloc((size_t)NN * BB * 4);
    float* h1    = (float*)alloc((size_t)NN * BB * 4);

    hipMemsetAsync(zbase, 0, zbytes, stream);

    k_count<<<(NE / 4 + 255) / 256, 256, 0, stream>>>(src, dst, cnt_out, cnt_in);
    k_coefscale<<<(NN * BB) / 256, 256, 0, stream>>>(in_feat, cnt_out, cnt_in, co, ci, xf);
    k_scan<<<1, 256, 0, stream>>>(cnt_in, rowptr, cursor);
    k_fill<<<(NE / 4 + 255) / 256, 256, 0, stream>>>(src, dst, cursor, csr);
    k_agg0pw<<<NN / 4, 256, 0, stream>>>(rowptr, csr, xf, ci, co, W0, b0, W1, y);
    k_agg1<<<NN / 4, 256, 0, stream>>>(rowptr, csr, y, ci, b1, h1);
    k_gemm<<<dim3(7, NSPLIT), 256, 0, stream>>>(h1, lw0, out1acc);
    k_mlp23<<<BB, 128, 0, stream>>>(out1acc, lb0, lw2, lb2, lw3, lb3, out);
}